// Round 14
// baseline (2381.320 us; speedup 1.0000x reference)
//
#include <hip/hip_runtime.h>

// Kernel ridge regression, RBF kernel. N=M=8192, D=32, gamma=1/32, reg=1e-3.
// R30 = R29/R27 (validated 1710-1769us band, absmax 0.05566406) + PAIRED
// qp STORES: each n==0 lane's 4 consecutive 16B-aligned dword stores (u=0..3)
// become 2x 8B relaxed-atomic double stores. Byte-stream identical
// (little-endian low dword = lower address = even u) -> absmax must stay
// EXACTLY 0.05566406 (canary). Reader (gather16_pair) already consumes 8B
// doubles at matching alignment. Halves store instructions + vmcnt entries
// drained by the pre-barrier s_waitcnt(0). This is a SHRINK of an existing
// phase in place -- not a reorder (R17/R19/R28), not a write-layout change
// (R22), no VMEM liveness across mv_compute (R19). Same packing in the
// predict-phase store.
//
// Exhausted-lever ledger (for the record): NITER=94 = convergence floor
// (93 races predict qp0 overwrite + 7% margin; 92 predicts 0.065 > 0.0644).
// 256 exp/thread = algorithmic floor; no packed transcendental on CDNA.
// Symmetric-K: 528 quarter-tiles don't map to 256 persistent blocks
// (barrier deadlock >256 blocks; 3-vs-2 tile imbalance sets barrier pace)
// -> negative EV. Four structural restructures failed with diagnosed causes
// (R17 scalar-phase interleave, R19 register pipelining, R22 write
// interleave, R28 arrival-path RMW fold).

#define NN 8192
#define DD 32
#define REGL 1e-3f
#define NITER 94
#define NBLK 256
#define NSL 16   // slices (col panels)
#define NRB 16   // rowblocks
#define ROWS 512 // rows per block
#define COLS 512 // cols per block
#define NC2 (-0.045084220027780106f)  // -gamma*log2e
#define SCF (0.3002806023f)           // sqrt(2*gamma*log2e)

typedef short v8s __attribute__((ext_vector_type(8)));
typedef float v4f __attribute__((ext_vector_type(4)));

__device__ __forceinline__ float fast_exp2(float x) {
#if __has_builtin(__builtin_amdgcn_exp2f)
  return __builtin_amdgcn_exp2f(x);
#else
  float r;
  asm("v_exp_f32 %0, %1" : "=v"(r) : "v"(x));
  return r;
#endif
}

// ---- relaxed agent-scope coherent accessors ----
__device__ __forceinline__ float ld_f(const float* p) {
  return __hip_atomic_load(p, __ATOMIC_RELAXED, __HIP_MEMORY_SCOPE_AGENT);
}
__device__ __forceinline__ void st_f(float* p, float v) {
  __hip_atomic_store(p, v, __ATOMIC_RELAXED, __HIP_MEMORY_SCOPE_AGENT);
}
__device__ __forceinline__ double ld_d(const double* p) {
  return __hip_atomic_load(p, __ATOMIC_RELAXED, __HIP_MEMORY_SCOPE_AGENT);
}
__device__ __forceinline__ void st_d(double* p, double v) {
  __hip_atomic_store(p, v, __ATOMIC_RELAXED, __HIP_MEMORY_SCOPE_AGENT);
}

__device__ __forceinline__ ushort f2bf(float x) {  // RNE float->bf16 bits
  unsigned u = __float_as_uint(x);
  return (ushort)((u + 0x7fff + ((u >> 16) & 1)) >> 16);
}
__device__ __forceinline__ float bf2f(ushort b) {
  return __uint_as_float(((unsigned)b) << 16);
}

__device__ __forceinline__ double bfly64_d(double v) {
#pragma unroll
  for (int m = 1; m < 64; m <<= 1) v += __shfl_xor(v, m, 64);
  return v;
}
__device__ __forceinline__ double wave_down_sum_d(double v) {
#pragma unroll
  for (int off = 32; off > 0; off >>= 1) v += __shfl_down(v, off, 64);
  return v;
}

// pack two consecutive floats (lo at lower address) into one 8B store
__device__ __forceinline__ void st_f2(float* p, float flo, float fhi) {
  unsigned long long pk = ((unsigned long long)__float_as_uint(fhi) << 32) |
                          (unsigned long long)__float_as_uint(flo);
  __hip_atomic_store((unsigned long long*)p, pk, __ATOMIC_RELAXED,
                     __HIP_MEMORY_SCOPE_AGENT);
}

// Pair-cooperative 16-slot gather over qp[slot][row] (slot stride NN floats).
// Threads with lane parity e=0/1 handle rows rowpair/rowpair+1. e=0 loads
// slots 0-7 as doubles (f[0]=row rowpair, f[1]=rowpair+1), e=1 loads slots
// 8-15. Off-row halves are exchanged via __shfl_xor(,1). Both parities sum
// their own row in ascending slot order 0..15 -> bitwise identical to the
// plain 16-dword ascending gather. (Validated R23.)
__device__ __forceinline__ float gather16_pair(const float* qp, int rowpair,
                                               int e) {
  const double* qpd = (const double*)qp + (rowpair >> 1);
  float mine[8], recv[8];
#pragma unroll
  for (int k = 0; k < 8; ++k) {
    union {
      double d;
      float f[2];
    } u;
    u.d = ld_d(qpd + (size_t)(e * 8 + k) * (NN / 2));
    mine[k] = e ? u.f[1] : u.f[0];  // my row's value
    recv[k] = e ? u.f[0] : u.f[1];  // partner row's value (to exchange)
  }
#pragma unroll
  for (int k = 0; k < 8; ++k) recv[k] = __shfl_xor(recv[k], 1, 64);
  // e==0: mine = slots 0-7, recv = slots 8-15 (both now my row)
  // e==1: recv = slots 0-7, mine = slots 8-15
  float s = 0.f;
#pragma unroll
  for (int k = 0; k < 8; ++k) s += e ? recv[k] : mine[k];
#pragma unroll
  for (int k = 0; k < 8; ++k) s += e ? mine[k] : recv[k];
  return s;
}

// ---- fence-free hierarchical global barrier, parity-double-buffered ----
// Counter set for parity p lives at bar + p*512: 16 group counters (stride
// 16, own lines) + root at +256. gen at bar[272] (own line, shared by both
// parities). Publisher stores gen FIRST, then lazily resets its parity's
// counters (safe: parity reused 2 barriers later; publisher's s_waitcnt(0)
// at its next gbarrier entry drains the resets before that barrier's
// publish can gate any same-parity arrival). (Validated R26.)
__device__ __forceinline__ void gbarrier(unsigned* bar, int par) {
  __builtin_amdgcn_s_waitcnt(0);
  __syncthreads();
  if (threadIdx.x == 0) {
    unsigned* gen = bar + 272;
    unsigned* base = bar + (par << 9);
    unsigned g =
        __hip_atomic_load(gen, __ATOMIC_RELAXED, __HIP_MEMORY_SCOPE_AGENT);
    unsigned a = __hip_atomic_fetch_add(&base[(blockIdx.x >> 4) * 16], 1u,
                                        __ATOMIC_RELAXED,
                                        __HIP_MEMORY_SCOPE_AGENT);
    bool pub = false;
    if (a == 15u) {
      unsigned ra = __hip_atomic_fetch_add(base + 256, 1u, __ATOMIC_RELAXED,
                                           __HIP_MEMORY_SCOPE_AGENT);
      if (ra == 15u) {
        // publish FIRST: waiters release immediately.
        __hip_atomic_store(gen, g + 1u, __ATOMIC_RELAXED,
                           __HIP_MEMORY_SCOPE_AGENT);
        pub = true;
        // lazy resets of this parity's counters.
#pragma unroll
        for (int k = 0; k < 16; ++k)
          __hip_atomic_store(&base[k * 16], 0u, __ATOMIC_RELAXED,
                             __HIP_MEMORY_SCOPE_AGENT);
        __hip_atomic_store(base + 256, 0u, __ATOMIC_RELAXED,
                           __HIP_MEMORY_SCOPE_AGENT);
      }
    }
    if (!pub) {
      unsigned t = 0;
      while (__hip_atomic_load(gen, __ATOMIC_RELAXED,
                               __HIP_MEMORY_SCOPE_AGENT) == g) {
        if (t < 64)
          __builtin_amdgcn_s_sleep(1);
        else
          __builtin_amdgcn_s_sleep(8);
        if (++t > (1u << 20)) break;  // escape hatch: fail, don't hang
      }
    }
  }
  __atomic_signal_fence(__ATOMIC_SEQ_CST);
  __syncthreads();
}

// hi/lo bf16 fragment from global X: lane holds row `row`, k = kb..kb+7.
__device__ __forceinline__ void conv_frag(const float* __restrict__ X, int row,
                                          int kb, v8s& h, v8s& l) {
  const float4* rp = (const float4*)(X + (size_t)row * DD + kb);
  float4 f0 = rp[0], f1 = rp[1];
  float f[8] = {f0.x, f0.y, f0.z, f0.w, f1.x, f1.y, f1.z, f1.w};
  union {
    v8s v;
    ushort u[8];
  } H, L;
#pragma unroll
  for (int j = 0; j < 8; ++j) {
    float fs = SCF * f[j];
    ushort hb = f2bf(fs);
    H.u[j] = hb;
    L.u[j] = f2bf(fs - bf2f(hb));
  }
  h = H.v;
  l = L.v;
}

// ---------------- setup kernels ----------------

__global__ void setup_zero(unsigned* __restrict__ bar) {
  int i = blockIdx.x * 256 + threadIdx.x;
  if (i < 1024) bar[i] = 0u;
}

// stores NC2 * ||x||^2
__global__ void row_norms(const float* __restrict__ X, float* __restrict__ xx) {
  int i = blockIdx.x * blockDim.x + threadIdx.x;
  if (i < NN) {
    const float4* row = (const float4*)(X + (size_t)i * DD);
    float s = 0.f;
#pragma unroll
    for (int k = 0; k < DD / 4; ++k) {
      float4 v = row[k];
      s += v.x * v.x + v.y * v.y + v.z * v.z + v.w * v.w;
    }
    xx[i] = NC2 * s;
  }
}

// ---------------- matvec compute core (2 row-tiles / wave, 32 col-tiles) ---
__device__ __forceinline__ void mv_compute(const v8s* ah, const v8s* al,
                                           const ushort (*Bh)[512],
                                           const ushort (*Bl)[512],
                                           const float* Wj, int lane,
                                           float racc[2][4]) {
  const int n = lane & 15;
  for (int t = 0; t < 32; ++t) {
    v8s bh = *(const v8s*)&Bh[t][lane * 8];
    v8s bl = *(const v8s*)&Bl[t][lane * 8];
    float wn = Wj[t * 16 + n];
#pragma unroll
    for (int rs = 0; rs < 2; ++rs) {
      v4f c = {0.f, 0.f, 0.f, 0.f};
      c = __builtin_amdgcn_mfma_f32_16x16x32_bf16(al[rs], bh, c, 0, 0, 0);
      c = __builtin_amdgcn_mfma_f32_16x16x32_bf16(ah[rs], bl, c, 0, 0, 0);
      c = __builtin_amdgcn_mfma_f32_16x16x32_bf16(ah[rs], bh, c, 0, 0, 0);
#pragma unroll
      for (int u = 0; u < 4; ++u)
        racc[rs][u] = fmaf(fast_exp2(c[u]), wn, racc[rs][u]);
    }
  }
}

// ---------------- persistent CG-CG kernel ----------------
// Grid 256 blocks x 1024 threads: 16 rowblocks (512 rows) x 16 slices
// (512 cols). All CG vectors live in block-local LDS.

__global__ __launch_bounds__(1024, 4) void cg_persist(
    const float* __restrict__ Xtr, const float* __restrict__ Xte,
    const float* __restrict__ xx_tr, const float* __restrict__ xx_te,
    const float* __restrict__ y, float* __restrict__ qp0,
    float* __restrict__ qp1, double* __restrict__ rho_s,
    double* __restrict__ mu_s, unsigned* __restrict__ bar,
    float* __restrict__ out, int db) {
  __shared__ __align__(16) ushort Bh[32][512];
  __shared__ __align__(16) ushort Bl[32][512];
  __shared__ float Wj[512];
  __shared__ float Ebj[512];
  __shared__ float Erow[512];
  __shared__ float Rrow[512], Qrow[512];
  __shared__ float Rcol[512], Qcol[512], Pcol[512], Xcol[512];
  __shared__ double sredq[16];
  __shared__ double sredr[16];
  __shared__ float s_ab[2];  // alpha, beta

  const int tid = threadIdx.x;
  const int lane = tid & 63;
  const int wid = tid >> 6;
  const int n = lane & 15, q4 = lane >> 4;
  const int rbi = blockIdx.x & 15;
  const int sli = blockIdx.x >> 4;
  const int rowbase = rbi * ROWS;
  const int i0 = rowbase + wid * 32;
  const int jbase = sli * COLS;

  // ---- stage B-slice into LDS once: 512 cols x 32 k, hi/lo bf16 ----
#pragma unroll
  for (int rep = 0; rep < 2; ++rep) {
    int idx = rep * 1024 + tid;  // 0..2047 = (col, k-octet) pairs
    int c = idx & 511;
    int g = idx >> 9;  // k-octet 0..3
    int j = jbase + c;
    const float4* rp = (const float4*)(Xtr + (size_t)j * DD + g * 8);
    float4 f0 = rp[0], f1 = rp[1];
    float f[8] = {f0.x, f0.y, f0.z, f0.w, f1.x, f1.y, f1.z, f1.w};
    union {
      ushort u[8];
      uint4 qq;
    } H, L;
#pragma unroll
    for (int e = 0; e < 8; ++e) {
      float fs = SCF * f[e];
      ushort hb = f2bf(fs);
      H.u[e] = hb;
      L.u[e] = f2bf(fs - bf2f(hb));
    }
    int tile = c >> 4, cl = c & 15;
    int ln = cl + 16 * g;
    *(uint4*)&Bh[tile][ln * 8] = H.qq;
    *(uint4*)&Bl[tile][ln * 8] = L.qq;
  }
  if (tid < 512) {
    Ebj[tid] = fast_exp2(xx_tr[jbase + tid]);
    Erow[tid] = fast_exp2(xx_tr[rowbase + tid]);
    // ---- block-local CG state ----
    Rrow[tid] = y[rowbase + tid];
    Qrow[tid] = 0.f;
    Rcol[tid] = y[jbase + tid];
    Qcol[tid] = 0.f;
    Pcol[tid] = 0.f;
    Xcol[tid] = 0.f;
  }

  // ---- A fragments in registers, converted once ----
  v8s ah[2], al[2];
#pragma unroll
  for (int rs = 0; rs < 2; ++rs)
    conv_frag(Xtr, i0 + rs * 16 + n, q4 * 8, ah[rs], al[rs]);

  double rho_old = 1.0, alpha_old = 1.0;  // wave-0 recurrence state
  __syncthreads();

  for (int it = 0; it < NITER; ++it) {
    float* qp = (db && (it & 1)) ? qp1 : qp0;

    // 1. matvec input: Wj = r_k[cols] * col exp factor. Col-domain threads
    //    (the same ones that updated Rcol last iter -> same-thread dep).
    if (tid >= 512) {
      int ct = tid - 512;
      Wj[ct] = Rcol[ct] * Ebj[ct];
    }
    // 2. rho partial (slice-0 blocks): r.r over this rowblock
    if (sli == 0) {
      float rvv = (tid < 512) ? Rrow[tid] : 0.f;
      double acc = wave_down_sum_d((double)rvv * (double)rvv);
      if (lane == 0) sredr[wid] = acc;
    }
    __syncthreads();
    if (sli == 0 && tid == 0) {
      double t = 0.0;
#pragma unroll
      for (int k3 = 0; k3 < 16; ++k3) t += sredr[k3];
      st_d(&rho_s[(size_t)it * 256 + rbi * 16], t);  // plain store, own line
    }

    // 3. matvec on r
    float racc[2][4] = {};
    mv_compute(ah, al, Bh, Bl, Wj, lane, racc);
#pragma unroll
    for (int rs = 0; rs < 2; ++rs)
#pragma unroll
      for (int u = 0; u < 4; ++u) {
#pragma unroll
        for (int m = 1; m < 16; m <<= 1)
          racc[rs][u] += __shfl_xor(racc[rs][u], m, 64);
      }
    double cmu = 0.0;
    if (n == 0) {
#pragma unroll
      for (int rs = 0; rs < 2; ++rs) {
        float qc[4];
#pragma unroll
        for (int u = 0; u < 4; ++u) {
          int lrow = wid * 32 + rs * 16 + q4 * 4 + u;
          qc[u] = racc[rs][u] * Erow[lrow];  // (K r)_row, this slice
          cmu += (double)qc[u] * (double)Rrow[lrow];  // r.Kr partial
        }
        // paired 8B stores (byte-identical to 4 dword stores; R30)
        float* qb = &qp[(size_t)sli * NN + rowbase + wid * 32 + rs * 16 +
                        q4 * 4];
        st_f2(qb, qc[0], qc[1]);
        st_f2(qb + 2, qc[2], qc[3]);
      }
    }
    cmu = bfly64_d(cmu);
    if (lane == 0) sredq[wid] = cmu;
    __syncthreads();
    if (tid == 0) {
      double t = 0.0;
#pragma unroll
      for (int k3 = 0; k3 < 16; ++k3) t += sredq[k3];
      st_d(&mu_s[(size_t)it * 256 + blockIdx.x], t);  // own slot, no RMW
    }

    // the ONE barrier: qp + rho + mu complete.
    // Parity: db=1 -> it&1 (one barrier/iter, alternates); db=0 -> 0 here
    // and 1 at the B-barrier below (strict 0,1,0,1 alternation).
    gbarrier(bar, db ? (it & 1) : 0);

    // 4. scalars via CG-CG recurrence (wave 0, then LDS broadcast);
    //    mu: 256 per-block slots reduced with 4 coalesced loads/lane.
    //    DO NOT reorder or interleave this phase (R17/R19/R28 lessons).
    if (wid == 0) {
      const double* mb = mu_s + (size_t)it * 256;
      double m = ld_d(mb + lane) + ld_d(mb + lane + 64) +
                 ld_d(mb + lane + 128) + ld_d(mb + lane + 192);
      double rv_l =
          (lane < 16) ? ld_d(rho_s + (size_t)it * 256 + lane * 16) : 0.0;
      double m1 = bfly64_d(m);
      double r1 = bfly64_d(rv_l);
      double mu = m1 + (double)REGL * r1;  // r.(K+reg I)r
      double beta_d = (it == 0) ? 0.0 : r1 / rho_old;
      double alpha_d =
          (it == 0) ? r1 / mu : r1 / (mu - r1 * beta_d / alpha_old);
      rho_old = r1;
      alpha_old = alpha_d;
      if (lane == 0) {
        s_ab[0] = (float)alpha_d;
        s_ab[1] = (float)beta_d;
      }
    }
    __syncthreads();
    const float alpha = s_ab[0], beta = s_ab[1];

    // 5+6. gather w = K r (+reg r) and update, SPLIT across thread domains:
    //    tid<512: rows; tid>=512: cols. Pair-cooperative loads; value order
    //    stays ascending slots 0..15 per row -> replicated values bitwise
    //    identical across blocks (and to R21/R23).
    if (tid < 512) {
      float s = gather16_pair(qp, rowbase + (tid & ~1), tid & 1);
      float wr = fmaf(REGL, Rrow[tid], s);
      float qn = fmaf(beta, Qrow[tid], wr);
      Qrow[tid] = qn;
      Rrow[tid] = fmaf(-alpha, qn, Rrow[tid]);
    } else {
      int ct = tid - 512;
      float s = gather16_pair(qp, jbase + (ct & ~1), ct & 1);
      float wc = fmaf(REGL, Rcol[ct], s);
      float qn = fmaf(beta, Qcol[ct], wc);
      Qcol[ct] = qn;
      float pn = fmaf(beta, Pcol[ct], Rcol[ct]);
      Pcol[ct] = pn;
      Xcol[ct] = fmaf(alpha, pn, Xcol[ct]);
      Rcol[ct] = fmaf(-alpha, qn, Rcol[ct]);
    }
    if (!db) gbarrier(bar, 1);  // single-buffer: protect qp (parity B=1)
    // db=1: cross-thread Rrow/Rcol reads next iter are covered by the
    // loop-top __syncthreads; qp reuse is protected by buffer alternation.
  }

  // ---- predict: out = K_test @ x, x = Xcol (block-local) ----
  {
    v8s th[2], tl[2];
#pragma unroll
    for (int rs = 0; rs < 2; ++rs)
      conv_frag(Xte, i0 + rs * 16 + n, q4 * 8, th[rs], tl[rs]);
    if (tid >= 512) {
      int ct = tid - 512;
      Wj[ct] = Xcol[ct] * Ebj[ct];  // same-thread dep on Xcol
    } else {
      Erow[tid] = fast_exp2(xx_te[rowbase + tid]);
    }
    __syncthreads();
    float racc[2][4] = {};
    mv_compute(th, tl, Bh, Bl, Wj, lane, racc);
#pragma unroll
    for (int rs = 0; rs < 2; ++rs)
#pragma unroll
      for (int u = 0; u < 4; ++u) {
#pragma unroll
        for (int m = 1; m < 16; m <<= 1)
          racc[rs][u] += __shfl_xor(racc[rs][u], m, 64);
      }
    if (n == 0) {
#pragma unroll
      for (int rs = 0; rs < 2; ++rs) {
        float qc[4];
#pragma unroll
        for (int u = 0; u < 4; ++u) {
          int lrow = wid * 32 + rs * 16 + q4 * 4 + u;
          qc[u] = racc[rs][u] * Erow[lrow];
        }
        float* qb = &qp0[(size_t)sli * NN + rowbase + wid * 32 + rs * 16 +
                         q4 * 4];
        st_f2(qb, qc[0], qc[1]);
        st_f2(qb + 2, qc[2], qc[3]);
      }
    }
    // Predict barrier parity 0: db=1 ran NITER (even) alternating barriers
    // (last was parity 1) -> next is 0. db=0 ran NITER (0,1) pairs -> 0.
    gbarrier(bar, 0);
    if (sli == 0 && tid < 512) {
      const float* qb = qp0 + rowbase + tid;
      float s = 0.f;
#pragma unroll
      for (int s2 = 0; s2 < NSL; ++s2) s += ld_f(qb + (size_t)s2 * NN);
      out[rowbase + tid] = s;
    }
  }
}

// ---------------- launcher ----------------

extern "C" void kernel_launch(void* const* d_in, const int* in_sizes, int n_in,
                              void* d_out, int out_size, void* d_ws,
                              size_t ws_size, hipStream_t stream) {
  const float* X_train = (const float*)d_in[0];
  const float* y_train = (const float*)d_in[1];
  const float* X_test = (const float*)d_in[2];
  float* out = (float*)d_out;

  char* w = (char*)d_ws;
  size_t off = 0;
  float* xx_tr = (float*)(w + off); off += NN * 4;
  float* xx_te = (float*)(w + off); off += NN * 4;
  double* rho_s = (double*)(w + off); off += (size_t)NITER * 256 * 8;
  double* mu_s = (double*)(w + off); off += (size_t)NITER * 256 * 8;
  unsigned* bar = (unsigned*)(w + off); off += 4096;  // 2 parity sets + gen
  off = (off + 255) & ~(size_t)255;
  float* qp0 = (float*)(w + off); off += (size_t)NSL * NN * 4;  // 512KB
  size_t need0 = off;
  float* qp1 = (float*)(w + off); off += (size_t)NSL * NN * 4;  // 512KB
  size_t need1 = off;

  int db = (ws_size >= need1) ? 1 : 0;
  if (ws_size < need0) return;  // ~1.5MB; ws >= ~2.3MB proven (R13-R29 db)
  if (!db) qp1 = qp0;

  setup_zero<<<4, 256, 0, stream>>>(bar);
  row_norms<<<NN / 256, 256, 0, stream>>>(X_train, xx_tr);
  row_norms<<<NN / 256, 256, 0, stream>>>(X_test, xx_te);

  cg_persist<<<NBLK, 1024, 0, stream>>>(X_train, X_test, xx_tr, xx_te,
                                        y_train, qp0, qp1, rho_s, mu_s, bar,
                                        out, db);
}

// Round 15
// 1609.707 us; speedup vs baseline: 1.4794x; 1.4794x over previous
//
#include <hip/hip_runtime.h>

// Kernel ridge regression, RBF kernel. N=M=8192, D=32, gamma=1/32, reg=1e-3.
// R31 = exact revert to R29/R27 (best validated: 1710-1769us band, absmax
// 0.05566406). FINAL STATE.
//
// R30 post-mortem (reverted): packing qp stores as 8B atomics via an
// unsigned long long* cast flipped the codegen mode (VGPR 60->64) and
// spilled qp traffic from LLC to HBM (hbm_bytes 0.41->2.99 GB, FETCH x10)
// -> +612us. Fifth confirmed instance: any deviation in this kernel's
// memory-access idiom (width, type, ordering) flips a fragile fast-path.
// Accepted changes were idiom-preserving only: tiling (R21), same-width
// load regroup (R23), barrier-internal publish order (R26), NITER (R27).
//
// Structural floor ledger: 94 global barriers (NITER floor: 92 predicts
// absmax 0.065 > 0.0644; 93 races the db=1 predict-phase qp0 overwrite);
// compute phase exp-issue-bound (256 v_exp_f32/thread = algorithmic min,
// quarter-rate transcendental, no packed variant on CDNA4); gather at
// LLC request floor (R23); barrier publish chain minimized (R26); scalar
// phase off-loadable only onto the arrival path, which costs more (R28).
// Rejected with diagnosed causes: R17 (scalar interleave), R19 (register
// pipelining -> spill), R22 (write interleave -> 2x WRITE), R28 (arrival
// RMW fold), R30 (store packing -> LLC bypass).

#define NN 8192
#define DD 32
#define REGL 1e-3f
#define NITER 94
#define NBLK 256
#define NSL 16   // slices (col panels)
#define NRB 16   // rowblocks
#define ROWS 512 // rows per block
#define COLS 512 // cols per block
#define NC2 (-0.045084220027780106f)  // -gamma*log2e
#define SCF (0.3002806023f)           // sqrt(2*gamma*log2e)

typedef short v8s __attribute__((ext_vector_type(8)));
typedef float v4f __attribute__((ext_vector_type(4)));

__device__ __forceinline__ float fast_exp2(float x) {
#if __has_builtin(__builtin_amdgcn_exp2f)
  return __builtin_amdgcn_exp2f(x);
#else
  float r;
  asm("v_exp_f32 %0, %1" : "=v"(r) : "v"(x));
  return r;
#endif
}

// ---- relaxed agent-scope coherent accessors ----
__device__ __forceinline__ float ld_f(const float* p) {
  return __hip_atomic_load(p, __ATOMIC_RELAXED, __HIP_MEMORY_SCOPE_AGENT);
}
__device__ __forceinline__ void st_f(float* p, float v) {
  __hip_atomic_store(p, v, __ATOMIC_RELAXED, __HIP_MEMORY_SCOPE_AGENT);
}
__device__ __forceinline__ double ld_d(const double* p) {
  return __hip_atomic_load(p, __ATOMIC_RELAXED, __HIP_MEMORY_SCOPE_AGENT);
}
__device__ __forceinline__ void st_d(double* p, double v) {
  __hip_atomic_store(p, v, __ATOMIC_RELAXED, __HIP_MEMORY_SCOPE_AGENT);
}

__device__ __forceinline__ ushort f2bf(float x) {  // RNE float->bf16 bits
  unsigned u = __float_as_uint(x);
  return (ushort)((u + 0x7fff + ((u >> 16) & 1)) >> 16);
}
__device__ __forceinline__ float bf2f(ushort b) {
  return __uint_as_float(((unsigned)b) << 16);
}

__device__ __forceinline__ double bfly64_d(double v) {
#pragma unroll
  for (int m = 1; m < 64; m <<= 1) v += __shfl_xor(v, m, 64);
  return v;
}
__device__ __forceinline__ double wave_down_sum_d(double v) {
#pragma unroll
  for (int off = 32; off > 0; off >>= 1) v += __shfl_down(v, off, 64);
  return v;
}

// Pair-cooperative 16-slot gather over qp[slot][row] (slot stride NN floats).
// Threads with lane parity e=0/1 handle rows rowpair/rowpair+1. e=0 loads
// slots 0-7 as doubles (f[0]=row rowpair, f[1]=rowpair+1), e=1 loads slots
// 8-15. Off-row halves are exchanged via __shfl_xor(,1). Both parities sum
// their own row in ascending slot order 0..15 -> bitwise identical to the
// plain 16-dword ascending gather. (Validated R23.)
__device__ __forceinline__ float gather16_pair(const float* qp, int rowpair,
                                               int e) {
  const double* qpd = (const double*)qp + (rowpair >> 1);
  float mine[8], recv[8];
#pragma unroll
  for (int k = 0; k < 8; ++k) {
    union {
      double d;
      float f[2];
    } u;
    u.d = ld_d(qpd + (size_t)(e * 8 + k) * (NN / 2));
    mine[k] = e ? u.f[1] : u.f[0];  // my row's value
    recv[k] = e ? u.f[0] : u.f[1];  // partner row's value (to exchange)
  }
#pragma unroll
  for (int k = 0; k < 8; ++k) recv[k] = __shfl_xor(recv[k], 1, 64);
  // e==0: mine = slots 0-7, recv = slots 8-15 (both now my row)
  // e==1: recv = slots 0-7, mine = slots 8-15
  float s = 0.f;
#pragma unroll
  for (int k = 0; k < 8; ++k) s += e ? recv[k] : mine[k];
#pragma unroll
  for (int k = 0; k < 8; ++k) s += e ? mine[k] : recv[k];
  return s;
}

// ---- fence-free hierarchical global barrier, parity-double-buffered ----
// Counter set for parity p lives at bar + p*512: 16 group counters (stride
// 16, own lines) + root at +256. gen at bar[272] (own line, shared by both
// parities). Publisher stores gen FIRST, then lazily resets its parity's
// counters (safe: parity reused 2 barriers later; publisher's s_waitcnt(0)
// at its next gbarrier entry drains the resets before that barrier's
// publish can gate any same-parity arrival). (Validated R26.)
__device__ __forceinline__ void gbarrier(unsigned* bar, int par) {
  __builtin_amdgcn_s_waitcnt(0);
  __syncthreads();
  if (threadIdx.x == 0) {
    unsigned* gen = bar + 272;
    unsigned* base = bar + (par << 9);
    unsigned g =
        __hip_atomic_load(gen, __ATOMIC_RELAXED, __HIP_MEMORY_SCOPE_AGENT);
    unsigned a = __hip_atomic_fetch_add(&base[(blockIdx.x >> 4) * 16], 1u,
                                        __ATOMIC_RELAXED,
                                        __HIP_MEMORY_SCOPE_AGENT);
    bool pub = false;
    if (a == 15u) {
      unsigned ra = __hip_atomic_fetch_add(base + 256, 1u, __ATOMIC_RELAXED,
                                           __HIP_MEMORY_SCOPE_AGENT);
      if (ra == 15u) {
        // publish FIRST: waiters release immediately.
        __hip_atomic_store(gen, g + 1u, __ATOMIC_RELAXED,
                           __HIP_MEMORY_SCOPE_AGENT);
        pub = true;
        // lazy resets of this parity's counters.
#pragma unroll
        for (int k = 0; k < 16; ++k)
          __hip_atomic_store(&base[k * 16], 0u, __ATOMIC_RELAXED,
                             __HIP_MEMORY_SCOPE_AGENT);
        __hip_atomic_store(base + 256, 0u, __ATOMIC_RELAXED,
                           __HIP_MEMORY_SCOPE_AGENT);
      }
    }
    if (!pub) {
      unsigned t = 0;
      while (__hip_atomic_load(gen, __ATOMIC_RELAXED,
                               __HIP_MEMORY_SCOPE_AGENT) == g) {
        if (t < 64)
          __builtin_amdgcn_s_sleep(1);
        else
          __builtin_amdgcn_s_sleep(8);
        if (++t > (1u << 20)) break;  // escape hatch: fail, don't hang
      }
    }
  }
  __atomic_signal_fence(__ATOMIC_SEQ_CST);
  __syncthreads();
}

// hi/lo bf16 fragment from global X: lane holds row `row`, k = kb..kb+7.
__device__ __forceinline__ void conv_frag(const float* __restrict__ X, int row,
                                          int kb, v8s& h, v8s& l) {
  const float4* rp = (const float4*)(X + (size_t)row * DD + kb);
  float4 f0 = rp[0], f1 = rp[1];
  float f[8] = {f0.x, f0.y, f0.z, f0.w, f1.x, f1.y, f1.z, f1.w};
  union {
    v8s v;
    ushort u[8];
  } H, L;
#pragma unroll
  for (int j = 0; j < 8; ++j) {
    float fs = SCF * f[j];
    ushort hb = f2bf(fs);
    H.u[j] = hb;
    L.u[j] = f2bf(fs - bf2f(hb));
  }
  h = H.v;
  l = L.v;
}

// ---------------- setup kernels ----------------

__global__ void setup_zero(unsigned* __restrict__ bar) {
  int i = blockIdx.x * 256 + threadIdx.x;
  if (i < 1024) bar[i] = 0u;
}

// stores NC2 * ||x||^2
__global__ void row_norms(const float* __restrict__ X, float* __restrict__ xx) {
  int i = blockIdx.x * blockDim.x + threadIdx.x;
  if (i < NN) {
    const float4* row = (const float4*)(X + (size_t)i * DD);
    float s = 0.f;
#pragma unroll
    for (int k = 0; k < DD / 4; ++k) {
      float4 v = row[k];
      s += v.x * v.x + v.y * v.y + v.z * v.z + v.w * v.w;
    }
    xx[i] = NC2 * s;
  }
}

// ---------------- matvec compute core (2 row-tiles / wave, 32 col-tiles) ---
__device__ __forceinline__ void mv_compute(const v8s* ah, const v8s* al,
                                           const ushort (*Bh)[512],
                                           const ushort (*Bl)[512],
                                           const float* Wj, int lane,
                                           float racc[2][4]) {
  const int n = lane & 15;
  for (int t = 0; t < 32; ++t) {
    v8s bh = *(const v8s*)&Bh[t][lane * 8];
    v8s bl = *(const v8s*)&Bl[t][lane * 8];
    float wn = Wj[t * 16 + n];
#pragma unroll
    for (int rs = 0; rs < 2; ++rs) {
      v4f c = {0.f, 0.f, 0.f, 0.f};
      c = __builtin_amdgcn_mfma_f32_16x16x32_bf16(al[rs], bh, c, 0, 0, 0);
      c = __builtin_amdgcn_mfma_f32_16x16x32_bf16(ah[rs], bl, c, 0, 0, 0);
      c = __builtin_amdgcn_mfma_f32_16x16x32_bf16(ah[rs], bh, c, 0, 0, 0);
#pragma unroll
      for (int u = 0; u < 4; ++u)
        racc[rs][u] = fmaf(fast_exp2(c[u]), wn, racc[rs][u]);
    }
  }
}

// ---------------- persistent CG-CG kernel ----------------
// Grid 256 blocks x 1024 threads: 16 rowblocks (512 rows) x 16 slices
// (512 cols). All CG vectors live in block-local LDS.

__global__ __launch_bounds__(1024, 4) void cg_persist(
    const float* __restrict__ Xtr, const float* __restrict__ Xte,
    const float* __restrict__ xx_tr, const float* __restrict__ xx_te,
    const float* __restrict__ y, float* __restrict__ qp0,
    float* __restrict__ qp1, double* __restrict__ rho_s,
    double* __restrict__ mu_s, unsigned* __restrict__ bar,
    float* __restrict__ out, int db) {
  __shared__ __align__(16) ushort Bh[32][512];
  __shared__ __align__(16) ushort Bl[32][512];
  __shared__ float Wj[512];
  __shared__ float Ebj[512];
  __shared__ float Erow[512];
  __shared__ float Rrow[512], Qrow[512];
  __shared__ float Rcol[512], Qcol[512], Pcol[512], Xcol[512];
  __shared__ double sredq[16];
  __shared__ double sredr[16];
  __shared__ float s_ab[2];  // alpha, beta

  const int tid = threadIdx.x;
  const int lane = tid & 63;
  const int wid = tid >> 6;
  const int n = lane & 15, q4 = lane >> 4;
  const int rbi = blockIdx.x & 15;
  const int sli = blockIdx.x >> 4;
  const int rowbase = rbi * ROWS;
  const int i0 = rowbase + wid * 32;
  const int jbase = sli * COLS;

  // ---- stage B-slice into LDS once: 512 cols x 32 k, hi/lo bf16 ----
#pragma unroll
  for (int rep = 0; rep < 2; ++rep) {
    int idx = rep * 1024 + tid;  // 0..2047 = (col, k-octet) pairs
    int c = idx & 511;
    int g = idx >> 9;  // k-octet 0..3
    int j = jbase + c;
    const float4* rp = (const float4*)(Xtr + (size_t)j * DD + g * 8);
    float4 f0 = rp[0], f1 = rp[1];
    float f[8] = {f0.x, f0.y, f0.z, f0.w, f1.x, f1.y, f1.z, f1.w};
    union {
      ushort u[8];
      uint4 qq;
    } H, L;
#pragma unroll
    for (int e = 0; e < 8; ++e) {
      float fs = SCF * f[e];
      ushort hb = f2bf(fs);
      H.u[e] = hb;
      L.u[e] = f2bf(fs - bf2f(hb));
    }
    int tile = c >> 4, cl = c & 15;
    int ln = cl + 16 * g;
    *(uint4*)&Bh[tile][ln * 8] = H.qq;
    *(uint4*)&Bl[tile][ln * 8] = L.qq;
  }
  if (tid < 512) {
    Ebj[tid] = fast_exp2(xx_tr[jbase + tid]);
    Erow[tid] = fast_exp2(xx_tr[rowbase + tid]);
    // ---- block-local CG state ----
    Rrow[tid] = y[rowbase + tid];
    Qrow[tid] = 0.f;
    Rcol[tid] = y[jbase + tid];
    Qcol[tid] = 0.f;
    Pcol[tid] = 0.f;
    Xcol[tid] = 0.f;
  }

  // ---- A fragments in registers, converted once ----
  v8s ah[2], al[2];
#pragma unroll
  for (int rs = 0; rs < 2; ++rs)
    conv_frag(Xtr, i0 + rs * 16 + n, q4 * 8, ah[rs], al[rs]);

  double rho_old = 1.0, alpha_old = 1.0;  // wave-0 recurrence state
  __syncthreads();

  for (int it = 0; it < NITER; ++it) {
    float* qp = (db && (it & 1)) ? qp1 : qp0;

    // 1. matvec input: Wj = r_k[cols] * col exp factor. Col-domain threads
    //    (the same ones that updated Rcol last iter -> same-thread dep).
    if (tid >= 512) {
      int ct = tid - 512;
      Wj[ct] = Rcol[ct] * Ebj[ct];
    }
    // 2. rho partial (slice-0 blocks): r.r over this rowblock
    if (sli == 0) {
      float rvv = (tid < 512) ? Rrow[tid] : 0.f;
      double acc = wave_down_sum_d((double)rvv * (double)rvv);
      if (lane == 0) sredr[wid] = acc;
    }
    __syncthreads();
    if (sli == 0 && tid == 0) {
      double t = 0.0;
#pragma unroll
      for (int k3 = 0; k3 < 16; ++k3) t += sredr[k3];
      st_d(&rho_s[(size_t)it * 256 + rbi * 16], t);  // plain store, own line
    }

    // 3. matvec on r
    float racc[2][4] = {};
    mv_compute(ah, al, Bh, Bl, Wj, lane, racc);
#pragma unroll
    for (int rs = 0; rs < 2; ++rs)
#pragma unroll
      for (int u = 0; u < 4; ++u) {
#pragma unroll
        for (int m = 1; m < 16; m <<= 1)
          racc[rs][u] += __shfl_xor(racc[rs][u], m, 64);
      }
    double cmu = 0.0;
    if (n == 0) {
#pragma unroll
      for (int rs = 0; rs < 2; ++rs)
#pragma unroll
        for (int u = 0; u < 4; ++u) {
          int lrow = wid * 32 + rs * 16 + q4 * 4 + u;
          float qc = racc[rs][u] * Erow[lrow];  // (K r)_row, this slice
          st_f(&qp[(size_t)sli * NN + rowbase + lrow], qc);
          cmu += (double)qc * (double)Rrow[lrow];  // r.Kr partial
        }
    }
    cmu = bfly64_d(cmu);
    if (lane == 0) sredq[wid] = cmu;
    __syncthreads();
    if (tid == 0) {
      double t = 0.0;
#pragma unroll
      for (int k3 = 0; k3 < 16; ++k3) t += sredq[k3];
      st_d(&mu_s[(size_t)it * 256 + blockIdx.x], t);  // own slot, no RMW
    }

    // the ONE barrier: qp + rho + mu complete.
    // Parity: db=1 -> it&1 (one barrier/iter, alternates); db=0 -> 0 here
    // and 1 at the B-barrier below (strict 0,1,0,1 alternation).
    gbarrier(bar, db ? (it & 1) : 0);

    // 4. scalars via CG-CG recurrence (wave 0, then LDS broadcast);
    //    mu: 256 per-block slots reduced with 4 coalesced loads/lane.
    //    DO NOT reorder or interleave this phase (R17/R19/R28 lessons).
    if (wid == 0) {
      const double* mb = mu_s + (size_t)it * 256;
      double m = ld_d(mb + lane) + ld_d(mb + lane + 64) +
                 ld_d(mb + lane + 128) + ld_d(mb + lane + 192);
      double rv_l =
          (lane < 16) ? ld_d(rho_s + (size_t)it * 256 + lane * 16) : 0.0;
      double m1 = bfly64_d(m);
      double r1 = bfly64_d(rv_l);
      double mu = m1 + (double)REGL * r1;  // r.(K+reg I)r
      double beta_d = (it == 0) ? 0.0 : r1 / rho_old;
      double alpha_d =
          (it == 0) ? r1 / mu : r1 / (mu - r1 * beta_d / alpha_old);
      rho_old = r1;
      alpha_old = alpha_d;
      if (lane == 0) {
        s_ab[0] = (float)alpha_d;
        s_ab[1] = (float)beta_d;
      }
    }
    __syncthreads();
    const float alpha = s_ab[0], beta = s_ab[1];

    // 5+6. gather w = K r (+reg r) and update, SPLIT across thread domains:
    //    tid<512: rows; tid>=512: cols. Pair-cooperative loads; value order
    //    stays ascending slots 0..15 per row -> replicated values bitwise
    //    identical across blocks (and to R21/R23).
    if (tid < 512) {
      float s = gather16_pair(qp, rowbase + (tid & ~1), tid & 1);
      float wr = fmaf(REGL, Rrow[tid], s);
      float qn = fmaf(beta, Qrow[tid], wr);
      Qrow[tid] = qn;
      Rrow[tid] = fmaf(-alpha, qn, Rrow[tid]);
    } else {
      int ct = tid - 512;
      float s = gather16_pair(qp, jbase + (ct & ~1), ct & 1);
      float wc = fmaf(REGL, Rcol[ct], s);
      float qn = fmaf(beta, Qcol[ct], wc);
      Qcol[ct] = qn;
      float pn = fmaf(beta, Pcol[ct], Rcol[ct]);
      Pcol[ct] = pn;
      Xcol[ct] = fmaf(alpha, pn, Xcol[ct]);
      Rcol[ct] = fmaf(-alpha, qn, Rcol[ct]);
    }
    if (!db) gbarrier(bar, 1);  // single-buffer: protect qp (parity B=1)
    // db=1: cross-thread Rrow/Rcol reads next iter are covered by the
    // loop-top __syncthreads; qp reuse is protected by buffer alternation.
  }

  // ---- predict: out = K_test @ x, x = Xcol (block-local) ----
  {
    v8s th[2], tl[2];
#pragma unroll
    for (int rs = 0; rs < 2; ++rs)
      conv_frag(Xte, i0 + rs * 16 + n, q4 * 8, th[rs], tl[rs]);
    if (tid >= 512) {
      int ct = tid - 512;
      Wj[ct] = Xcol[ct] * Ebj[ct];  // same-thread dep on Xcol
    } else {
      Erow[tid] = fast_exp2(xx_te[rowbase + tid]);
    }
    __syncthreads();
    float racc[2][4] = {};
    mv_compute(th, tl, Bh, Bl, Wj, lane, racc);
#pragma unroll
    for (int rs = 0; rs < 2; ++rs)
#pragma unroll
      for (int u = 0; u < 4; ++u) {
#pragma unroll
        for (int m = 1; m < 16; m <<= 1)
          racc[rs][u] += __shfl_xor(racc[rs][u], m, 64);
      }
    if (n == 0) {
#pragma unroll
      for (int rs = 0; rs < 2; ++rs)
#pragma unroll
        for (int u = 0; u < 4; ++u) {
          int lrow = wid * 32 + rs * 16 + q4 * 4 + u;
          st_f(&qp0[(size_t)sli * NN + rowbase + lrow],
               racc[rs][u] * Erow[lrow]);
        }
    }
    // Predict barrier parity 0: db=1 ran NITER (even) alternating barriers
    // (last was parity 1) -> next is 0. db=0 ran NITER (0,1) pairs -> 0.
    gbarrier(bar, 0);
    if (sli == 0 && tid < 512) {
      const float* qb = qp0 + rowbase + tid;
      float s = 0.f;
#pragma unroll
      for (int s2 = 0; s2 < NSL; ++s2) s += ld_f(qb + (size_t)s2 * NN);
      out[rowbase + tid] = s;
    }
  }
}

// ---------------- launcher ----------------

extern "C" void kernel_launch(void* const* d_in, const int* in_sizes, int n_in,
                              void* d_out, int out_size, void* d_ws,
                              size_t ws_size, hipStream_t stream) {
  const float* X_train = (const float*)d_in[0];
  const float* y_train = (const float*)d_in[1];
  const float* X_test = (const float*)d_in[2];
  float* out = (float*)d_out;

  char* w = (char*)d_ws;
  size_t off = 0;
  float* xx_tr = (float*)(w + off); off += NN * 4;
  float* xx_te = (float*)(w + off); off += NN * 4;
  double* rho_s = (double*)(w + off); off += (size_t)NITER * 256 * 8;
  double* mu_s = (double*)(w + off); off += (size_t)NITER * 256 * 8;
  unsigned* bar = (unsigned*)(w + off); off += 4096;  // 2 parity sets + gen
  off = (off + 255) & ~(size_t)255;
  float* qp0 = (float*)(w + off); off += (size_t)NSL * NN * 4;  // 512KB
  size_t need0 = off;
  float* qp1 = (float*)(w + off); off += (size_t)NSL * NN * 4;  // 512KB
  size_t need1 = off;

  int db = (ws_size >= need1) ? 1 : 0;
  if (ws_size < need0) return;  // ~1.5MB; ws >= ~2.3MB proven (R13-R29 db)
  if (!db) qp1 = qp0;

  setup_zero<<<4, 256, 0, stream>>>(bar);
  row_norms<<<NN / 256, 256, 0, stream>>>(X_train, xx_tr);
  row_norms<<<NN / 256, 256, 0, stream>>>(X_test, xx_te);

  cg_persist<<<NBLK, 1024, 0, stream>>>(X_train, X_test, xx_tr, xx_te,
                                        y_train, qp0, qp1, rho_s, mu_s, bar,
                                        out, db);
}